// Round 9
// baseline (256.167 us; speedup 1.0000x reference)
//
#include <hip/hip_runtime.h>

#define N_NODES 50000
#define N_EDGES 400000
#define N_TILES 782          // ceil(50000/64)
#define NPADROW (N_TILES * 64)   // 50048 padded node rows for G8
#define GRID_HALF 391        // tile stride for k_nodeGS roles (2 tiles per block)
#define AGG_BLOCKS 2048      // 8 blocks/CU (16 KB LDS, 4 waves/block); persistent

#define N_PAD   50176        // 196 * 256
#define NBLK    196

// k_prep_w segment offsets (thread ids)
#define PZ_CNT   50176                    // [0, PZ_CNT): zero counts
#define PO_TB    (PZ_CNT)                 // 8192: Tb (bf16, linear perm2 = type-major)
#define PO_W1EB  (PO_TB + 8192)           // 65536: W1ebT
#define PO_W2E   (PO_W1EB + 65536)        // 65536: W2eT (perm2 k)
#define PO_W1S   (PO_W2E + 65536)         // 32768: W1sT
#define PO_W2S   (PO_W1S + 32768)         // 32768: W2sT
#define PO_FEAT  (PO_W2S + 32768)         // 200192: features -> bf16 swizzled tiles
#define P_TOTAL  (PO_FEAT + N_TILES * 256)  // 455168 = 1778 * 256

typedef __attribute__((ext_vector_type(8))) short short8;
typedef __attribute__((ext_vector_type(4))) float floatx4;
typedef __attribute__((ext_vector_type(2))) float floatx2;

typedef __attribute__((address_space(3))) unsigned int lds_u32;
typedef __attribute__((address_space(1))) const unsigned int glb_u32;

__device__ __forceinline__ float bf2f(unsigned short u) {
    union { unsigned int i; float f; } v; v.i = ((unsigned int)u) << 16; return v.f;
}
__device__ __forceinline__ float u2f(unsigned int u) {
    union { unsigned int i; float f; } v; v.i = u; return v.f;
}
__device__ __forceinline__ unsigned short f2bf(float f) {
    union { float f; unsigned int i; } v; v.f = f;
    unsigned int b = v.i;
    return (unsigned short)((b + 0x7FFFu + ((b >> 16) & 1u)) >> 16);
}

// async 16B/lane global->LDS copy; l must be wave-uniform base, g is per-lane
__device__ __forceinline__ void async_cp16(const unsigned short* __restrict__ g,
                                           unsigned short* l) {
    __builtin_amdgcn_global_load_lds((glb_u32*)g, (lds_u32*)l, 16, 0, 0);
}

// G8 column permutation: logical col c = w3|ct2|r4 bits (w = wave 0..7)
// stored at pos = w*64 + r*4 + ct  -> each thread's 4 ct-bytes are one dword
__device__ __forceinline__ int perm2(int c) {
    return (c & 0x3C0) | ((c & 15) << 2) | ((c >> 4) & 3);
}
__device__ __forceinline__ int inv2(int p) {
    return (p & 0x3C0) | ((p & 3) << 4) | ((p >> 2) & 15);
}

// ---------------- weight prep + counts zero + feature bf16 pre-swizzle (fused) ----------------
__device__ __forceinline__ void tr_seg(const float* __restrict__ src, unsigned short* __restrict__ dst,
                                       int K, int Ncols, int idx) {
    int c = idx / K, k = idx - c * K;
    dst[idx] = f2bf(src[k * Ncols + c]);
}

__global__ void k_prep_w(const float* __restrict__ e_emb, const float* __restrict__ W1e,
                         const float* __restrict__ b1e, const float* __restrict__ W2e,
                         const float* __restrict__ W1s, const float* __restrict__ W2s,
                         const float* __restrict__ features,
                         unsigned short* __restrict__ Tb, unsigned short* __restrict__ W1ebT,
                         unsigned short* __restrict__ W2eT, unsigned short* __restrict__ W1sT,
                         unsigned short* __restrict__ W2sT, unsigned short* __restrict__ Fb,
                         int* __restrict__ counts) {
    int tid = blockIdx.x * 256 + threadIdx.x;
    if (tid < PZ_CNT) {
        counts[tid] = 0;
    } else if (tid < PO_W1EB) {
        int idx = tid - PO_TB;
        int typ = idx >> 9, col = idx & 511;
        float acc = b1e[col];
        for (int k = 0; k < 128; ++k)
            acc += e_emb[typ * 128 + k] * W1e[k * 512 + col];
        // linear perm2 layout: lane l's 8 T-values = 16 contiguous bytes (1 ds_read_b128)
        Tb[typ * 512 + perm2(col)] = f2bf(acc);
    } else if (tid < PO_W2E) {
        tr_seg(W1e + 128 * 512, W1ebT, 128, 512, tid - PO_W1EB);
    } else if (tid < PO_W1S) {
        // W2eT[c][kp] over permuted kp (H column space): logical k = inv2(kp)
        int idx = tid - PO_W2E;
        int c = idx >> 9, kp = idx & 511;
        W2eT[idx] = f2bf(W2e[inv2(kp) * 128 + c]);
    } else if (tid < PO_W2S) {
        tr_seg(W1s, W1sT, 128, 256, tid - PO_W1S);
    } else if (tid < PO_FEAT) {
        tr_seg(W2s, W2sT, 256, 128, tid - PO_W2S);
    } else {
        // features f32 -> bf16, tile-major, XOR-swizzled (exact fbs layout)
        int idx = tid - PO_FEAT;
        int tile = idx >> 8, t = idx & 255;
        int row = t >> 2, seg = t & 3;
        int node = tile * 64 + row; if (node >= N_NODES) node = N_NODES - 1;
        const float* p = &features[(size_t)node * 128 + seg * 32];
        unsigned short* dst = &Fb[(size_t)tile * 8192 + row * 128];
        #pragma unroll
        for (int i = 0; i < 4; ++i) {
            float4 x = *(const float4*)&p[i * 8];
            float4 y = *(const float4*)&p[i * 8 + 4];
            short8 hv;
            hv[0] = (short)f2bf(x.x); hv[1] = (short)f2bf(x.y);
            hv[2] = (short)f2bf(x.z); hv[3] = (short)f2bf(x.w);
            hv[4] = (short)f2bf(y.x); hv[5] = (short)f2bf(y.y);
            hv[6] = (short)f2bf(y.z); hv[7] = (short)f2bf(y.w);
            int c = seg * 4 + i;
            *(short8*)&dst[(c ^ (row & 7)) * 8] = hv;
        }
    }
}

// ---------------- counting sort of edges by dst (parallel 3-kernel scan) ----------------

__global__ void k_hist(const int* __restrict__ edge_dst, int* __restrict__ counts) {
    int e = blockIdx.x * 256 + threadIdx.x;
    if (e < N_EDGES) atomicAdd(&counts[edge_dst[e]], 1);
}

__global__ void k_scan1(const int* __restrict__ counts, int* __restrict__ blocksum) {
    __shared__ int s[256];
    int t = threadIdx.x;
    s[t] = counts[blockIdx.x * 256 + t];
    __syncthreads();
    for (int d = 128; d > 0; d >>= 1) {
        if (t < d) s[t] += s[t + d];
        __syncthreads();
    }
    if (t == 0) blocksum[blockIdx.x] = s[0];
}

__global__ void k_scan2(const int* __restrict__ blocksum, int* __restrict__ blockoff) {
    __shared__ int s[256];
    int t = threadIdx.x;
    int v = (t < NBLK) ? blocksum[t] : 0;
    s[t] = v;
    __syncthreads();
    for (int d = 1; d < 256; d <<= 1) {
        int x = (t >= d) ? s[t - d] : 0;
        __syncthreads();
        s[t] += x;
        __syncthreads();
    }
    if (t < NBLK) blockoff[t] = s[t] - v;
}

__global__ void k_scan3(const int* __restrict__ counts, const int* __restrict__ blockoff,
                        int* __restrict__ row_start, int* __restrict__ cursor) {
    __shared__ int s[256];
    int t = threadIdx.x;
    int i = blockIdx.x * 256 + t;
    int v = counts[i];
    s[t] = v;
    __syncthreads();
    for (int d = 1; d < 256; d <<= 1) {
        int x = (t >= d) ? s[t - d] : 0;
        __syncthreads();
        s[t] += x;
        __syncthreads();
    }
    int excl = s[t] - v + blockoff[blockIdx.x];
    row_start[i] = excl;
    cursor[i] = excl;
}

// pack src|type<<16 (src < 65536)
__global__ void k_scatter(const int* __restrict__ edge_src, const int* __restrict__ edge_dst,
                          const int* __restrict__ edge_type, int* __restrict__ cursor,
                          int* __restrict__ sorted_pack) {
    int e = blockIdx.x * 256 + threadIdx.x;
    if (e < N_EDGES) {
        int d = edge_dst[e];
        int pos = atomicAdd(&cursor[d], 1);
        sorted_pack[pos] = edge_src[e] | (edge_type[e] << 16);
    }
}

// ---------------- MERGED k_nodeGS: G-role (G8 GEMM) / S-role (self MLP), one launch ----

__device__ __forceinline__ void stage16k_8w(const unsigned short* __restrict__ Fb,
                                            unsigned short* buf, int tile, int wv, int lane) {
    const unsigned short* src = Fb + (size_t)tile * 8192 + wv * 1024 + lane * 8;
    unsigned short* dst = buf + wv * 1024;
    #pragma unroll
    for (int i = 0; i < 2; ++i)
        async_cp16(src + i * 512, dst + i * 512);
}

__device__ __forceinline__ void gemmG_role(const unsigned short* __restrict__ Fb,
                                           const unsigned short* __restrict__ W1ebT,
                                           unsigned char* __restrict__ G8,
                                           unsigned short (*fbs)[64 * 128], int t0) {
    int t = threadIdx.x, lane = t & 63, wv = t >> 6;
    int r = lane & 15, quad = lane >> 4;

    stage16k_8w(Fb, fbs[0], t0, wv, lane);

    short8 bfrag[4][4];                   // 64 VGPR; wave owns cols wv*64..+64 of 512
    #pragma unroll
    for (int ct = 0; ct < 4; ++ct)
        #pragma unroll
        for (int ks = 0; ks < 4; ++ks)
            bfrag[ct][ks] = *(const short8*)&W1ebT[(wv * 64 + ct * 16 + r) * 128 + ks * 32 + quad * 8];

    int cur = 0;
    for (int tile = t0; tile < N_TILES; tile += GRID_HALF) {
        __syncthreads();                  // drains stage(cur) + protects buf(cur^1)
        int nxt = tile + GRID_HALF;
        if (nxt < N_TILES) stage16k_8w(Fb, fbs[cur ^ 1], nxt, wv, lane);
        int mbase = tile * 64;
        #pragma unroll
        for (int m = 0; m < 4; ++m) {
            floatx4 acc[4];
            #pragma unroll
            for (int i = 0; i < 4; ++i) acc[i] = (floatx4){0.f, 0.f, 0.f, 0.f};
            #pragma unroll
            for (int ks = 0; ks < 4; ++ks) {
                int row = m * 16 + r;
                int cp = (ks * 4 + quad) ^ (row & 7);
                short8 a = *(const short8*)&fbs[cur][row * 128 + cp * 8];
                #pragma unroll
                for (int ct = 0; ct < 4; ++ct)
                    acc[ct] = __builtin_amdgcn_mfma_f32_16x16x32_bf16(a, bfrag[ct][ks], acc[ct], 0, 0, 0);
            }
            // one packed dword store per node (perm2 layout)
            #pragma unroll
            for (int p = 0; p < 4; ++p) {
                int node = mbase + m * 16 + quad * 4 + p;
                int w0 = __builtin_amdgcn_cvt_pk_fp8_f32(acc[0][p], acc[1][p], 0, false);
                w0     = __builtin_amdgcn_cvt_pk_fp8_f32(acc[2][p], acc[3][p], w0, true);
                *(unsigned int*)&G8[(size_t)node * 512 + wv * 64 + r * 4] = (unsigned int)w0;
            }
        }
        cur ^= 1;
    }
}

__device__ __forceinline__ void self_role(const unsigned short* __restrict__ Fb,
                                          const unsigned short* __restrict__ W1sT,
                                          const float* __restrict__ b1s,
                                          const unsigned short* __restrict__ W2sT,
                                          const float* __restrict__ b2s,
                                          float* __restrict__ out,
                                          unsigned short (*fbs)[64 * 128],
                                          unsigned short* hss, int t0) {
    int t = threadIdx.x, lane = t & 63, wv = t >> 6;
    int r = lane & 15, quad = lane >> 4;

    stage16k_8w(Fb, fbs[0], t0, wv, lane);

    short8 b1f[2][4];                              // 32 VGPR
    #pragma unroll
    for (int ct = 0; ct < 2; ++ct)
        #pragma unroll
        for (int ks = 0; ks < 4; ++ks)
            b1f[ct][ks] = *(const short8*)&W1sT[(wv * 32 + ct * 16 + r) * 128 + ks * 32 + quad * 8];
    short8 b2f[8];                                 // 32 VGPR
    #pragma unroll
    for (int ks = 0; ks < 8; ++ks)
        b2f[ks] = *(const short8*)&W2sT[(wv * 16 + r) * 256 + ks * 32 + quad * 8];
    float bias1[2];
    #pragma unroll
    for (int ct = 0; ct < 2; ++ct) bias1[ct] = b1s[wv * 32 + ct * 16 + r];
    float bias2 = b2s[wv * 16 + r];

    int cur = 0;
    for (int tile = t0; tile < N_TILES; tile += GRID_HALF) {
        __syncthreads();                  // drains stage(cur); hss reads of prev iter done
        int nxt = tile + GRID_HALF;
        if (nxt < N_TILES) stage16k_8w(Fb, fbs[cur ^ 1], nxt, wv, lane);
        int mbase = tile * 64;

        // GEMM1: hidden = relu(feat @ W1s + b1s) -> hss (XOR-swizzled)
        #pragma unroll
        for (int m = 0; m < 4; ++m) {
            floatx4 acc[2];
            #pragma unroll
            for (int i = 0; i < 2; ++i) acc[i] = (floatx4){0.f, 0.f, 0.f, 0.f};
            #pragma unroll
            for (int ks = 0; ks < 4; ++ks) {
                int row = m * 16 + r;
                int cp = (ks * 4 + quad) ^ (row & 7);
                short8 a = *(const short8*)&fbs[cur][row * 128 + cp * 8];
                #pragma unroll
                for (int ct = 0; ct < 2; ++ct)
                    acc[ct] = __builtin_amdgcn_mfma_f32_16x16x32_bf16(a, b1f[ct][ks], acc[ct], 0, 0, 0);
            }
            #pragma unroll
            for (int ct = 0; ct < 2; ++ct)
                #pragma unroll
                for (int p = 0; p < 4; ++p) {
                    int lrow = m * 16 + quad * 4 + p;
                    int col = wv * 32 + ct * 16 + r;
                    float v = fmaxf(acc[ct][p] + bias1[ct], 0.f);
                    int cp = (col >> 3) ^ (lrow & 7);
                    hss[lrow * 256 + cp * 8 + (col & 7)] = f2bf(v);
                }
        }
        // lgkm-only barrier: do NOT drain vmcnt (keeps next-tile stage in flight)
        asm volatile("s_waitcnt lgkmcnt(0)" ::: "memory");
        __builtin_amdgcn_s_barrier();
        __builtin_amdgcn_sched_barrier(0);

        // GEMM2: out[:, :128] = hidden @ W2s + b2s
        #pragma unroll
        for (int m = 0; m < 4; ++m) {
            floatx4 acc2 = (floatx4){0.f, 0.f, 0.f, 0.f};
            #pragma unroll
            for (int ks = 0; ks < 8; ++ks) {
                int row = m * 16 + r;
                int cp = (ks * 4 + quad) ^ (row & 7);
                short8 a = *(const short8*)&hss[row * 256 + cp * 8];
                acc2 = __builtin_amdgcn_mfma_f32_16x16x32_bf16(a, b2f[ks], acc2, 0, 0, 0);
            }
            #pragma unroll
            for (int p = 0; p < 4; ++p) {
                int node = mbase + m * 16 + quad * 4 + p;
                if (node < N_NODES)
                    out[(size_t)node * 256 + wv * 16 + r] = acc2[p] + bias2;
            }
        }
        cur ^= 1;
    }
}

__global__ __launch_bounds__(512, 4) void k_nodeGS(const unsigned short* __restrict__ Fb,
                                                   const unsigned short* __restrict__ W1ebT,
                                                   unsigned char* __restrict__ G8,
                                                   const unsigned short* __restrict__ W1sT,
                                                   const float* __restrict__ b1s,
                                                   const unsigned short* __restrict__ W2sT,
                                                   const float* __restrict__ b2s,
                                                   float* __restrict__ out) {
    __shared__ unsigned short fbs[2][64 * 128];   // 2 x 16 KB
    __shared__ unsigned short hss[64 * 256];      // 32 KB (S-role only)
    int bid = blockIdx.x;
    if (bid < GRID_HALF)
        gemmG_role(Fb, W1ebT, G8, fbs, bid);
    else
        self_role(Fb, W1sT, b1s, W2sT, b2s, out, fbs, hss, bid - GRID_HALF);
}

// ---------------- aggregation: H[n] = sum_e relu(G[src]+T[type])   [N,512] bf16 ----------------
// PERSISTENT, 8 blocks/CU (16 KB LDS). T linear perm2 in LDS -> ONE ds_read_b128 per edge.
// Dual-node per wave: two independent 4-edge streams -> 8 gathers in flight, B-stream
// gather latency hides under A-stream VALU.

__global__ __launch_bounds__(256) void k_agg(const unsigned char* __restrict__ G8,
                                             const unsigned short* __restrict__ Tb,
                                             const int* __restrict__ row_start,
                                             const int* __restrict__ sorted_pack,
                                             unsigned short* __restrict__ H) {
    __shared__ unsigned short tls[16 * 512];   // 16 KB: T bf16, linear perm2 (type-major)
    int t = threadIdx.x;
    {
        const int4* Tw = (const int4*)Tb;
        int4* Ld = (int4*)tls;
        #pragma unroll
        for (int i = 0; i < 4; ++i)
            Ld[i * 256 + t] = Tw[i * 256 + t];
    }
    __syncthreads();

    int lane = t & 63;
    int wid = __builtin_amdgcn_readfirstlane(t >> 6);   // provably wave-uniform
    int goff = lane * 8;                       // byte offset into 512-B fp8 row (perm2 cols)
    const uint4* tb = (const uint4*)&tls[lane * 8];   // + type*64 -> lane's 16B of that type
    const floatx2 zf = {0.f, 0.f};

#define EDGE(VV, A) {                                                          \
        unsigned vv = (unsigned)(VV);                                          \
        int2 g = *(const int2*)&G8[(size_t)(vv & 0xFFFFu) * 512 + goff];       \
        uint4 tw = tb[(vv >> 16) * 64];                                        \
        floatx2 t0 = {u2f(tw.x << 16), u2f(tw.x & 0xFFFF0000u)};               \
        floatx2 t1 = {u2f(tw.y << 16), u2f(tw.y & 0xFFFF0000u)};               \
        floatx2 t2 = {u2f(tw.z << 16), u2f(tw.z & 0xFFFF0000u)};               \
        floatx2 t3 = {u2f(tw.w << 16), u2f(tw.w & 0xFFFF0000u)};               \
        floatx2 z0 = __builtin_amdgcn_cvt_pk_f32_fp8(g.x, false) + t0;         \
        floatx2 z1 = __builtin_amdgcn_cvt_pk_f32_fp8(g.x, true)  + t1;         \
        floatx2 z2 = __builtin_amdgcn_cvt_pk_f32_fp8(g.y, false) + t2;         \
        floatx2 z3 = __builtin_amdgcn_cvt_pk_f32_fp8(g.y, true)  + t3;         \
        A[0] += __builtin_elementwise_max(z0, zf);                             \
        A[1] += __builtin_elementwise_max(z1, zf);                             \
        A[2] += __builtin_elementwise_max(z2, zf);                             \
        A[3] += __builtin_elementwise_max(z3, zf);                             \
    }

    for (int nb = blockIdx.x * 8 + wid * 2; nb < N_NODES; nb += AGG_BLOCKS * 8) {
        bool two = (nb + 1 < N_NODES);
        int ea = __builtin_amdgcn_readfirstlane(row_start[nb]);
        int ma = __builtin_amdgcn_readfirstlane(row_start[nb + 1]);
        int eb = ma;
        int mb = two ? __builtin_amdgcn_readfirstlane(row_start[nb + 2]) : ma;

        floatx2 A[4] = {zf, zf, zf, zf};
        floatx2 B[4] = {zf, zf, zf, zf};

        // joint loop: two independent 4-edge streams (8 gathers in flight)
        while (ea + 4 <= ma && eb + 4 <= mb) {
            const int* spa = sorted_pack + ea;
            const int* spb = sorted_pack + eb;
            int a0 = spa[0], a1 = spa[1], a2 = spa[2], a3 = spa[3];
            int b0 = spb[0], b1 = spb[1], b2 = spb[2], b3 = spb[3];
            EDGE(a0, A); EDGE(b0, B);
            EDGE(a1, A); EDGE(b1, B);
            EDGE(a2, A); EDGE(b2, B);
            EDGE(a3, A); EDGE(b3, B);
            ea += 4; eb += 4;
        }
        // tails
        for (; ea + 4 <= ma; ea += 4) {
            const int* sp = sorted_pack + ea;
            int v0 = sp[0], v1 = sp[1], v2 = sp[2], v3 = sp[3];
            EDGE(v0, A); EDGE(v1, A); EDGE(v2, A); EDGE(v3, A);
        }
        for (; ea < ma; ++ea) EDGE(sorted_pack[ea], A);
        for (; eb + 4 <= mb; eb += 4) {
            const int* sp = sorted_pack + eb;
            int v0 = sp[0], v1 = sp[1], v2 = sp[2], v3 = sp[3];
            EDGE(v0, B); EDGE(v1, B); EDGE(v2, B); EDGE(v3, B);
        }
        for (; eb < mb; ++eb) EDGE(sorted_pack[eb], B);

        short8 hv;
        hv[0] = (short)f2bf(A[0].x); hv[1] = (short)f2bf(A[0].y);
        hv[2] = (short)f2bf(A[1].x); hv[3] = (short)f2bf(A[1].y);
        hv[4] = (short)f2bf(A[2].x); hv[5] = (short)f2bf(A[2].y);
        hv[6] = (short)f2bf(A[3].x); hv[7] = (short)f2bf(A[3].y);
        // store XOR-swizzled so k_gemm_H can stage with linear global_load_lds
        *(short8*)&H[(size_t)nb * 512 + ((lane ^ (nb & 7)) * 8)] = hv;
        if (two) {
            int n1 = nb + 1;
            short8 hw;
            hw[0] = (short)f2bf(B[0].x); hw[1] = (short)f2bf(B[0].y);
            hw[2] = (short)f2bf(B[1].x); hw[3] = (short)f2bf(B[1].y);
            hw[4] = (short)f2bf(B[2].x); hw[5] = (short)f2bf(B[2].y);
            hw[6] = (short)f2bf(B[3].x); hw[7] = (short)f2bf(B[3].y);
            *(short8*)&H[(size_t)n1 * 512 + ((lane ^ (n1 & 7)) * 8)] = hw;
        }
    }
#undef EDGE
}

// ---------------- out[:,128:] = H @ W2e + deg*b2e  (512 thr, bf register-resident) ----------------
__global__ __launch_bounds__(512, 4) void k_gemm_H(const unsigned short* __restrict__ H,
                                                   const int* __restrict__ row_start,
                                                   const unsigned short* __restrict__ W2eT,
                                                   const float* __restrict__ b2e,
                                                   float* __restrict__ out) {
    __shared__ unsigned short hls[64 * 512];   // 64 KB
    int t = threadIdx.x, lane = t & 63, wv = t >> 6;
    int r = lane & 15, quad = lane >> 4;
    int tile = blockIdx.x;

    // async stage: H tile is pre-swizzled, 8 KB per wave
    {
        const unsigned short* src = H + (size_t)tile * 32768 + wv * 4096 + lane * 8;
        unsigned short* dst = hls + wv * 4096;
        #pragma unroll
        for (int i = 0; i < 8; ++i)
            async_cp16(src + i * 512, dst + i * 512);
    }

    short8 bf[16];                              // 64 VGPR, register-resident
    #pragma unroll
    for (int ks = 0; ks < 16; ++ks)
        bf[ks] = *(const short8*)&W2eT[(wv * 16 + r) * 512 + ks * 32 + quad * 8];
    float bias = b2e[wv * 16 + r];

    __syncthreads();   // drains stage

    int nbase = tile * 64;
    #pragma unroll
    for (int m = 0; m < 4; ++m) {
        floatx4 acc = (floatx4){0.f, 0.f, 0.f, 0.f};
        #pragma unroll
        for (int ks = 0; ks < 16; ++ks) {
            int row = m * 16 + r;
            int cp = (ks * 4 + quad) ^ (row & 7);
            short8 a = *(const short8*)&hls[row * 512 + cp * 8];
            acc = __builtin_amdgcn_mfma_f32_16x16x32_bf16(a, bf[ks], acc, 0, 0, 0);
        }
        #pragma unroll
        for (int p = 0; p < 4; ++p) {
            int node = nbase + m * 16 + quad * 4 + p;
            if (node < N_NODES) {
                float dg = (float)(row_start[node + 1] - row_start[node]);
                out[(size_t)node * 256 + 128 + wv * 16 + r] = acc[p] + dg * bias;
            }
        }
    }
}

// ---------------- launch ----------------

extern "C" void kernel_launch(void* const* d_in, const int* in_sizes, int n_in,
                              void* d_out, int out_size, void* d_ws, size_t ws_size,
                              hipStream_t stream) {
    const float* features  = (const float*)d_in[0];
    const int*   edge_src  = (const int*)d_in[1];
    const int*   edge_dst  = (const int*)d_in[2];
    const int*   edge_type = (const int*)d_in[3];
    const float* e_emb     = (const float*)d_in[4];
    const float* W1e       = (const float*)d_in[5];
    const float* b1e       = (const float*)d_in[6];
    const float* W2e       = (const float*)d_in[7];
    const float* b2e       = (const float*)d_in[8];
    const float* W1s       = (const float*)d_in[9];
    const float* b1s       = (const float*)d_in[10];
    const float* W2s       = (const float*)d_in[11];
    const float* b2s       = (const float*)d_in[12];
    float* out = (float*)d_out;

    char* ws = (char*)d_ws;
    size_t off = 0;
    auto alloc = [&](size_t bytes) {
        char* p = ws + off;
        off += (bytes + 255) & ~(size_t)255;
        return p;
    };
    unsigned char*  G8       = (unsigned char*)alloc((size_t)NPADROW * 512);
    unsigned short* H        = (unsigned short*)alloc((size_t)NPADROW * 512 * 2);
    unsigned short* Fb       = (unsigned short*)alloc((size_t)N_TILES * 8192 * 2);
    unsigned short* Tb       = (unsigned short*)alloc(16 * 512 * 2);
    unsigned short* W1ebT    = (unsigned short*)alloc(512 * 128 * 2);
    unsigned short* W2eT     = (unsigned short*)alloc(128 * 512 * 2);
    unsigned short* W1sT     = (unsigned short*)alloc(256 * 128 * 2);
    unsigned short* W2sT     = (unsigned short*)alloc(128 * 256 * 2);
    int* counts      = (int*)alloc((size_t)N_PAD * 4);
    int* row_start   = (int*)alloc((size_t)N_PAD * 4);
    int* cursor      = (int*)alloc((size_t)N_PAD * 4);
    int* blocksum    = (int*)alloc(256 * 4);
    int* blockoff    = (int*)alloc(256 * 4);
    int* sorted_pack = (int*)alloc((size_t)N_EDGES * 4);

    k_prep_w<<<P_TOTAL / 256, 256, 0, stream>>>(e_emb, W1e, b1e, W2e, W1s, W2s, features,
                                                Tb, W1ebT, W2eT, W1sT, W2sT, Fb, counts);

    k_hist<<<(N_EDGES + 255) / 256, 256, 0, stream>>>(edge_dst, counts);
    k_scan1<<<NBLK, 256, 0, stream>>>(counts, blocksum);
    k_scan2<<<1, 256, 0, stream>>>(blocksum, blockoff);
    k_scan3<<<NBLK, 256, 0, stream>>>(counts, blockoff, row_start, cursor);
    k_scatter<<<(N_EDGES + 255) / 256, 256, 0, stream>>>(edge_src, edge_dst, edge_type,
                                                         cursor, sorted_pack);

    k_nodeGS<<<2 * GRID_HALF, 512, 0, stream>>>(Fb, W1ebT, G8, W1sT, b1s, W2sT, b2s, out);
    k_agg<<<AGG_BLOCKS, 256, 0, stream>>>(G8, Tb, row_start, sorted_pack, H);
    k_gemm_H<<<N_TILES, 512, 0, stream>>>(H, row_start, W2eT, b2e, out);
}

// Round 10
// 249.188 us; speedup vs baseline: 1.0280x; 1.0280x over previous
//
#include <hip/hip_runtime.h>

#define N_NODES 50000
#define N_EDGES 400000
#define N_TILES 782          // ceil(50000/64)
#define NPADROW (N_TILES * 64)   // 50048 padded node rows for G8
#define GRID_HALF 391        // tile stride for k_nodeGS roles (2 tiles per block)
#define AGG_BLOCKS 2048      // 8 blocks/CU (16 KB LDS, 4 waves/block); persistent

#define N_PAD   50176        // 196 * 256
#define NBLK    196

// k_prep_w segment offsets (thread ids)
#define PZ_CNT   50176                    // [0, PZ_CNT): zero counts
#define PO_TB    (PZ_CNT)                 // 8192: Tb (bf16, linear perm2 = type-major)
#define PO_W1EB  (PO_TB + 8192)           // 65536: W1ebT
#define PO_W2E   (PO_W1EB + 65536)        // 65536: W2eT (perm2 k)
#define PO_W1S   (PO_W2E + 65536)         // 32768: W1sT
#define PO_W2S   (PO_W1S + 32768)         // 32768: W2sT
#define PO_FEAT  (PO_W2S + 32768)         // 200192: features -> bf16 swizzled tiles
#define P_TOTAL  (PO_FEAT + N_TILES * 256)  // 455168 = 1778 * 256

typedef __attribute__((ext_vector_type(8))) short short8;
typedef __attribute__((ext_vector_type(4))) float floatx4;
typedef __attribute__((ext_vector_type(2))) float floatx2;

typedef __attribute__((address_space(3))) unsigned int lds_u32;
typedef __attribute__((address_space(1))) const unsigned int glb_u32;

__device__ __forceinline__ float bf2f(unsigned short u) {
    union { unsigned int i; float f; } v; v.i = ((unsigned int)u) << 16; return v.f;
}
__device__ __forceinline__ float u2f(unsigned int u) {
    union { unsigned int i; float f; } v; v.i = u; return v.f;
}
__device__ __forceinline__ unsigned short f2bf(float f) {
    union { float f; unsigned int i; } v; v.f = f;
    unsigned int b = v.i;
    return (unsigned short)((b + 0x7FFFu + ((b >> 16) & 1u)) >> 16);
}

// async 16B/lane global->LDS copy; l must be wave-uniform base, g is per-lane
__device__ __forceinline__ void async_cp16(const unsigned short* __restrict__ g,
                                           unsigned short* l) {
    __builtin_amdgcn_global_load_lds((glb_u32*)g, (lds_u32*)l, 16, 0, 0);
}

// G8 column permutation: logical col c = w3|ct2|r4 bits (w = wave 0..7)
// stored at pos = w*64 + r*4 + ct  -> each thread's 4 ct-bytes are one dword
__device__ __forceinline__ int perm2(int c) {
    return (c & 0x3C0) | ((c & 15) << 2) | ((c >> 4) & 3);
}
__device__ __forceinline__ int inv2(int p) {
    return (p & 0x3C0) | ((p & 3) << 4) | ((p >> 2) & 15);
}

// ---------------- weight prep + counts zero + feature bf16 pre-swizzle (fused) ----------------
__device__ __forceinline__ void tr_seg(const float* __restrict__ src, unsigned short* __restrict__ dst,
                                       int K, int Ncols, int idx) {
    int c = idx / K, k = idx - c * K;
    dst[idx] = f2bf(src[k * Ncols + c]);
}

__global__ void k_prep_w(const float* __restrict__ e_emb, const float* __restrict__ W1e,
                         const float* __restrict__ b1e, const float* __restrict__ W2e,
                         const float* __restrict__ W1s, const float* __restrict__ W2s,
                         const float* __restrict__ features,
                         unsigned short* __restrict__ Tb, unsigned short* __restrict__ W1ebT,
                         unsigned short* __restrict__ W2eT, unsigned short* __restrict__ W1sT,
                         unsigned short* __restrict__ W2sT, unsigned short* __restrict__ Fb,
                         int* __restrict__ counts) {
    int tid = blockIdx.x * 256 + threadIdx.x;
    if (tid < PZ_CNT) {
        counts[tid] = 0;
    } else if (tid < PO_W1EB) {
        int idx = tid - PO_TB;
        int typ = idx >> 9, col = idx & 511;
        float acc = b1e[col];
        for (int k = 0; k < 128; ++k)
            acc += e_emb[typ * 128 + k] * W1e[k * 512 + col];
        // linear perm2 layout: lane l's 8 T-values = 16 contiguous bytes (1 ds_read_b128)
        Tb[typ * 512 + perm2(col)] = f2bf(acc);
    } else if (tid < PO_W2E) {
        tr_seg(W1e + 128 * 512, W1ebT, 128, 512, tid - PO_W1EB);
    } else if (tid < PO_W1S) {
        // W2eT[c][kp] over permuted kp (H column space): logical k = inv2(kp)
        int idx = tid - PO_W2E;
        int c = idx >> 9, kp = idx & 511;
        W2eT[idx] = f2bf(W2e[inv2(kp) * 128 + c]);
    } else if (tid < PO_W2S) {
        tr_seg(W1s, W1sT, 128, 256, tid - PO_W1S);
    } else if (tid < PO_FEAT) {
        tr_seg(W2s, W2sT, 256, 128, tid - PO_W2S);
    } else {
        // features f32 -> bf16, tile-major, XOR-swizzled (exact fbs layout)
        int idx = tid - PO_FEAT;
        int tile = idx >> 8, t = idx & 255;
        int row = t >> 2, seg = t & 3;
        int node = tile * 64 + row; if (node >= N_NODES) node = N_NODES - 1;
        const float* p = &features[(size_t)node * 128 + seg * 32];
        unsigned short* dst = &Fb[(size_t)tile * 8192 + row * 128];
        #pragma unroll
        for (int i = 0; i < 4; ++i) {
            float4 x = *(const float4*)&p[i * 8];
            float4 y = *(const float4*)&p[i * 8 + 4];
            short8 hv;
            hv[0] = (short)f2bf(x.x); hv[1] = (short)f2bf(x.y);
            hv[2] = (short)f2bf(x.z); hv[3] = (short)f2bf(x.w);
            hv[4] = (short)f2bf(y.x); hv[5] = (short)f2bf(y.y);
            hv[6] = (short)f2bf(y.z); hv[7] = (short)f2bf(y.w);
            int c = seg * 4 + i;
            *(short8*)&dst[(c ^ (row & 7)) * 8] = hv;
        }
    }
}

// ---------------- counting sort of edges by dst (2-kernel scan: scan2 fused into scan3) ----

__global__ void k_hist(const int* __restrict__ edge_dst, int* __restrict__ counts) {
    int e = blockIdx.x * 256 + threadIdx.x;
    if (e < N_EDGES) atomicAdd(&counts[edge_dst[e]], 1);
}

__global__ void k_scan1(const int* __restrict__ counts, int* __restrict__ blocksum) {
    __shared__ int s[256];
    int t = threadIdx.x;
    s[t] = counts[blockIdx.x * 256 + t];
    __syncthreads();
    for (int d = 128; d > 0; d >>= 1) {
        if (t < d) s[t] += s[t + d];
        __syncthreads();
    }
    if (t == 0) blocksum[blockIdx.x] = s[0];
}

// fused: each block computes its own block offset from blocksum (196 reads), then scans
__global__ void k_scan3(const int* __restrict__ counts, const int* __restrict__ blocksum,
                        int* __restrict__ row_start, int* __restrict__ cursor) {
    __shared__ int s[256];
    int t = threadIdx.x;
    // phase 1: inclusive prefix of blocksum (redundant per block, trivial cost)
    int vb = (t < NBLK) ? blocksum[t] : 0;
    s[t] = vb;
    __syncthreads();
    for (int d = 1; d < 256; d <<= 1) {
        int x = (t >= d) ? s[t - d] : 0;
        __syncthreads();
        s[t] += x;
        __syncthreads();
    }
    int boff = (blockIdx.x > 0) ? s[blockIdx.x - 1] : 0;   // exclusive block offset
    __syncthreads();
    // phase 2: counts scan within block
    int i = blockIdx.x * 256 + t;
    int v = counts[i];
    s[t] = v;
    __syncthreads();
    for (int d = 1; d < 256; d <<= 1) {
        int x = (t >= d) ? s[t - d] : 0;
        __syncthreads();
        s[t] += x;
        __syncthreads();
    }
    int excl = s[t] - v + boff;
    row_start[i] = excl;
    cursor[i] = excl;
}

// pack src|type<<16 (src < 65536)
__global__ void k_scatter(const int* __restrict__ edge_src, const int* __restrict__ edge_dst,
                          const int* __restrict__ edge_type, int* __restrict__ cursor,
                          int* __restrict__ sorted_pack) {
    int e = blockIdx.x * 256 + threadIdx.x;
    if (e < N_EDGES) {
        int d = edge_dst[e];
        int pos = atomicAdd(&cursor[d], 1);
        sorted_pack[pos] = edge_src[e] | (edge_type[e] << 16);
    }
}

// ---------------- MERGED k_nodeGS: G-role (G8 GEMM) / S-role (self MLP), one launch ----

__device__ __forceinline__ void stage16k_8w(const unsigned short* __restrict__ Fb,
                                            unsigned short* buf, int tile, int wv, int lane) {
    const unsigned short* src = Fb + (size_t)tile * 8192 + wv * 1024 + lane * 8;
    unsigned short* dst = buf + wv * 1024;
    #pragma unroll
    for (int i = 0; i < 2; ++i)
        async_cp16(src + i * 512, dst + i * 512);
}

__device__ __forceinline__ void gemmG_role(const unsigned short* __restrict__ Fb,
                                           const unsigned short* __restrict__ W1ebT,
                                           unsigned char* __restrict__ G8,
                                           unsigned short (*fbs)[64 * 128], int t0) {
    int t = threadIdx.x, lane = t & 63, wv = t >> 6;
    int r = lane & 15, quad = lane >> 4;

    stage16k_8w(Fb, fbs[0], t0, wv, lane);

    short8 bfrag[4][4];                   // 64 VGPR; wave owns cols wv*64..+64 of 512
    #pragma unroll
    for (int ct = 0; ct < 4; ++ct)
        #pragma unroll
        for (int ks = 0; ks < 4; ++ks)
            bfrag[ct][ks] = *(const short8*)&W1ebT[(wv * 64 + ct * 16 + r) * 128 + ks * 32 + quad * 8];

    int cur = 0;
    for (int tile = t0; tile < N_TILES; tile += GRID_HALF) {
        __syncthreads();                  // drains stage(cur) + protects buf(cur^1)
        int nxt = tile + GRID_HALF;
        if (nxt < N_TILES) stage16k_8w(Fb, fbs[cur ^ 1], nxt, wv, lane);
        int mbase = tile * 64;
        #pragma unroll
        for (int m = 0; m < 4; ++m) {
            floatx4 acc[4];
            #pragma unroll
            for (int i = 0; i < 4; ++i) acc[i] = (floatx4){0.f, 0.f, 0.f, 0.f};
            #pragma unroll
            for (int ks = 0; ks < 4; ++ks) {
                int row = m * 16 + r;
                int cp = (ks * 4 + quad) ^ (row & 7);
                short8 a = *(const short8*)&fbs[cur][row * 128 + cp * 8];
                #pragma unroll
                for (int ct = 0; ct < 4; ++ct)
                    acc[ct] = __builtin_amdgcn_mfma_f32_16x16x32_bf16(a, bfrag[ct][ks], acc[ct], 0, 0, 0);
            }
            // one packed dword store per node (perm2 layout)
            #pragma unroll
            for (int p = 0; p < 4; ++p) {
                int node = mbase + m * 16 + quad * 4 + p;
                int w0 = __builtin_amdgcn_cvt_pk_fp8_f32(acc[0][p], acc[1][p], 0, false);
                w0     = __builtin_amdgcn_cvt_pk_fp8_f32(acc[2][p], acc[3][p], w0, true);
                *(unsigned int*)&G8[(size_t)node * 512 + wv * 64 + r * 4] = (unsigned int)w0;
            }
        }
        cur ^= 1;
    }
}

__device__ __forceinline__ void self_role(const unsigned short* __restrict__ Fb,
                                          const unsigned short* __restrict__ W1sT,
                                          const float* __restrict__ b1s,
                                          const unsigned short* __restrict__ W2sT,
                                          const float* __restrict__ b2s,
                                          float* __restrict__ out,
                                          unsigned short (*fbs)[64 * 128],
                                          unsigned short* hss, int t0) {
    int t = threadIdx.x, lane = t & 63, wv = t >> 6;
    int r = lane & 15, quad = lane >> 4;

    stage16k_8w(Fb, fbs[0], t0, wv, lane);

    short8 b1f[2][4];                              // 32 VGPR
    #pragma unroll
    for (int ct = 0; ct < 2; ++ct)
        #pragma unroll
        for (int ks = 0; ks < 4; ++ks)
            b1f[ct][ks] = *(const short8*)&W1sT[(wv * 32 + ct * 16 + r) * 128 + ks * 32 + quad * 8];
    short8 b2f[8];                                 // 32 VGPR
    #pragma unroll
    for (int ks = 0; ks < 8; ++ks)
        b2f[ks] = *(const short8*)&W2sT[(wv * 16 + r) * 256 + ks * 32 + quad * 8];
    float bias1[2];
    #pragma unroll
    for (int ct = 0; ct < 2; ++ct) bias1[ct] = b1s[wv * 32 + ct * 16 + r];
    float bias2 = b2s[wv * 16 + r];

    int cur = 0;
    for (int tile = t0; tile < N_TILES; tile += GRID_HALF) {
        __syncthreads();                  // drains stage(cur); hss reads of prev iter done
        int nxt = tile + GRID_HALF;
        if (nxt < N_TILES) stage16k_8w(Fb, fbs[cur ^ 1], nxt, wv, lane);
        int mbase = tile * 64;

        // GEMM1: hidden = relu(feat @ W1s + b1s) -> hss (XOR-swizzled)
        #pragma unroll
        for (int m = 0; m < 4; ++m) {
            floatx4 acc[2];
            #pragma unroll
            for (int i = 0; i < 2; ++i) acc[i] = (floatx4){0.f, 0.f, 0.f, 0.f};
            #pragma unroll
            for (int ks = 0; ks < 4; ++ks) {
                int row = m * 16 + r;
                int cp = (ks * 4 + quad) ^ (row & 7);
                short8 a = *(const short8*)&fbs[cur][row * 128 + cp * 8];
                #pragma unroll
                for (int ct = 0; ct < 2; ++ct)
                    acc[ct] = __builtin_amdgcn_mfma_f32_16x16x32_bf16(a, b1f[ct][ks], acc[ct], 0, 0, 0);
            }
            #pragma unroll
            for (int ct = 0; ct < 2; ++ct)
                #pragma unroll
                for (int p = 0; p < 4; ++p) {
                    int lrow = m * 16 + quad * 4 + p;
                    int col = wv * 32 + ct * 16 + r;
                    float v = fmaxf(acc[ct][p] + bias1[ct], 0.f);
                    int cp = (col >> 3) ^ (lrow & 7);
                    hss[lrow * 256 + cp * 8 + (col & 7)] = f2bf(v);
                }
        }
        // lgkm-only barrier: do NOT drain vmcnt (keeps next-tile stage in flight)
        asm volatile("s_waitcnt lgkmcnt(0)" ::: "memory");
        __builtin_amdgcn_s_barrier();
        __builtin_amdgcn_sched_barrier(0);

        // GEMM2: out[:, :128] = hidden @ W2s + b2s
        #pragma unroll
        for (int m = 0; m < 4; ++m) {
            floatx4 acc2 = (floatx4){0.f, 0.f, 0.f, 0.f};
            #pragma unroll
            for (int ks = 0; ks < 8; ++ks) {
                int row = m * 16 + r;
                int cp = (ks * 4 + quad) ^ (row & 7);
                short8 a = *(const short8*)&hss[row * 256 + cp * 8];
                acc2 = __builtin_amdgcn_mfma_f32_16x16x32_bf16(a, b2f[ks], acc2, 0, 0, 0);
            }
            #pragma unroll
            for (int p = 0; p < 4; ++p) {
                int node = mbase + m * 16 + quad * 4 + p;
                if (node < N_NODES)
                    out[(size_t)node * 256 + wv * 16 + r] = acc2[p] + bias2;
            }
        }
        cur ^= 1;
    }
}

__global__ __launch_bounds__(512, 4) void k_nodeGS(const unsigned short* __restrict__ Fb,
                                                   const unsigned short* __restrict__ W1ebT,
                                                   unsigned char* __restrict__ G8,
                                                   const unsigned short* __restrict__ W1sT,
                                                   const float* __restrict__ b1s,
                                                   const unsigned short* __restrict__ W2sT,
                                                   const float* __restrict__ b2s,
                                                   float* __restrict__ out) {
    __shared__ unsigned short fbs[2][64 * 128];   // 2 x 16 KB
    __shared__ unsigned short hss[64 * 256];      // 32 KB (S-role only)
    int bid = blockIdx.x;
    if (bid < GRID_HALF)
        gemmG_role(Fb, W1ebT, G8, fbs, bid);
    else
        self_role(Fb, W1sT, b1s, W2sT, b2s, out, fbs, hss, bid - GRID_HALF);
}

// ---------------- aggregation: H[n] = sum_e relu(G[src]+T[type])   [N,512] bf16 ----------------
// PERSISTENT, 8 blocks/CU (16 KB LDS). R8 single-node 4-deep-prefetch loop; T linear
// perm2 in LDS -> ONE ds_read_b128 per edge (halved LDS-pipe cost vs R8's 4x b32).

__global__ __launch_bounds__(256) void k_agg(const unsigned char* __restrict__ G8,
                                             const unsigned short* __restrict__ Tb,
                                             const int* __restrict__ row_start,
                                             const int* __restrict__ sorted_pack,
                                             unsigned short* __restrict__ H) {
    __shared__ unsigned short tls[16 * 512];   // 16 KB: T bf16, linear perm2 (type-major)
    int t = threadIdx.x;
    {
        const int4* Tw = (const int4*)Tb;
        int4* Ld = (int4*)tls;
        #pragma unroll
        for (int i = 0; i < 4; ++i)
            Ld[i * 256 + t] = Tw[i * 256 + t];
    }
    __syncthreads();

    int lane = t & 63;
    int wid = __builtin_amdgcn_readfirstlane(t >> 6);   // provably wave-uniform
    int goff = lane * 8;                       // byte offset into 512-B fp8 row (perm2 cols)
    const uint4* tb = (const uint4*)&tls[lane * 8];   // + type*64 -> lane's 16B of that type
    const floatx2 zf = {0.f, 0.f};

    for (int node = blockIdx.x * 4 + wid; node < N_NODES; node += AGG_BLOCKS * 4) {
        int beg = __builtin_amdgcn_readfirstlane(row_start[node]);
        int end = __builtin_amdgcn_readfirstlane(row_start[node + 1]);

        floatx2 a0 = zf, a1 = zf, a2 = zf, a3 = zf;

#define EDGE(VV) {                                                             \
        unsigned vv = (unsigned)(VV);                                          \
        int2 g = *(const int2*)&G8[(size_t)(vv & 0xFFFFu) * 512 + goff];       \
        uint4 tw = tb[(vv >> 16) * 64];                                        \
        floatx2 t0 = {u2f(tw.x << 16), u2f(tw.x & 0xFFFF0000u)};               \
        floatx2 t1 = {u2f(tw.y << 16), u2f(tw.y & 0xFFFF0000u)};               \
        floatx2 t2 = {u2f(tw.z << 16), u2f(tw.z & 0xFFFF0000u)};               \
        floatx2 t3 = {u2f(tw.w << 16), u2f(tw.w & 0xFFFF0000u)};               \
        floatx2 z0 = __builtin_amdgcn_cvt_pk_f32_fp8(g.x, false) + t0;         \
        floatx2 z1 = __builtin_amdgcn_cvt_pk_f32_fp8(g.x, true)  + t1;         \
        floatx2 z2 = __builtin_amdgcn_cvt_pk_f32_fp8(g.y, false) + t2;         \
        floatx2 z3 = __builtin_amdgcn_cvt_pk_f32_fp8(g.y, true)  + t3;         \
        a0 += __builtin_elementwise_max(z0, zf);                               \
        a1 += __builtin_elementwise_max(z1, zf);                               \
        a2 += __builtin_elementwise_max(z2, zf);                               \
        a3 += __builtin_elementwise_max(z3, zf);                               \
    }

        int e = beg;
        int v0 = 0, v1 = 0, v2 = 0, v3 = 0;
        bool have = (e + 4 <= end);
        if (have) {
            v0 = sorted_pack[e];     v1 = sorted_pack[e + 1];
            v2 = sorted_pack[e + 2]; v3 = sorted_pack[e + 3];
        }
        while (have) {
            int c0 = v0, c1 = v1, c2 = v2, c3 = v3;
            e += 4;
            have = (e + 4 <= end);
            if (have) {                       // prefetch next group's packs
                v0 = sorted_pack[e];     v1 = sorted_pack[e + 1];
                v2 = sorted_pack[e + 2]; v3 = sorted_pack[e + 3];
            }
            EDGE(c0); EDGE(c1); EDGE(c2); EDGE(c3);
        }
        for (; e < end; ++e) {
            int v = sorted_pack[e];
            EDGE(v);
        }
#undef EDGE

        short8 hv;
        hv[0] = (short)f2bf(a0.x); hv[1] = (short)f2bf(a0.y);
        hv[2] = (short)f2bf(a1.x); hv[3] = (short)f2bf(a1.y);
        hv[4] = (short)f2bf(a2.x); hv[5] = (short)f2bf(a2.y);
        hv[6] = (short)f2bf(a3.x); hv[7] = (short)f2bf(a3.y);
        // store XOR-swizzled so k_gemm_H can stage with linear global_load_lds
        *(short8*)&H[(size_t)node * 512 + ((lane ^ (node & 7)) * 8)] = hv;
    }
}

// ---------------- out[:,128:] = H @ W2e + deg*b2e  (512 thr, bf register-resident) ----------------
__global__ __launch_bounds__(512, 4) void k_gemm_H(const unsigned short* __restrict__ H,
                                                   const int* __restrict__ row_start,
                                                   const unsigned short* __restrict__ W2eT,
                                                   const float* __restrict__ b2e,
                                                   float* __restrict__ out) {
    __shared__ unsigned short hls[64 * 512];   // 64 KB
    int t = threadIdx.x, lane = t & 63, wv = t >> 6;
    int r = lane & 15, quad = lane >> 4;
    int tile = blockIdx.x;

    // async stage: H tile is pre-swizzled, 8 KB per wave
    {
        const unsigned short* src = H + (size_t)tile * 32768 + wv * 4096 + lane * 8;
        unsigned short* dst = hls + wv * 4096;
        #pragma unroll
        for (int i = 0; i < 8; ++i)
            async_cp16(src + i * 512, dst + i * 512);
    }

    short8 bf[16];                              // 64 VGPR, register-resident
    #pragma unroll
    for (int ks = 0; ks < 16; ++ks)
        bf[ks] = *(const short8*)&W2eT[(wv * 16 + r) * 512 + ks * 32 + quad * 8];
    float bias = b2e[wv * 16 + r];

    __syncthreads();   // drains stage

    int nbase = tile * 64;
    #pragma unroll
    for (int m = 0; m < 4; ++m) {
        floatx4 acc = (floatx4){0.f, 0.f, 0.f, 0.f};
        #pragma unroll
        for (int ks = 0; ks < 16; ++ks) {
            int row = m * 16 + r;
            int cp = (ks * 4 + quad) ^ (row & 7);
            short8 a = *(const short8*)&hls[row * 512 + cp * 8];
            acc = __builtin_amdgcn_mfma_f32_16x16x32_bf16(a, bf[ks], acc, 0, 0, 0);
        }
        #pragma unroll
        for (int p = 0; p < 4; ++p) {
            int node = nbase + m * 16 + quad * 4 + p;
            if (node < N_NODES) {
                float dg = (float)(row_start[node + 1] - row_start[node]);
                out[(size_t)node * 256 + 128 + wv * 16 + r] = acc[p] + dg * bias;
            }
        }
    }
}

// ---------------- launch ----------------

extern "C" void kernel_launch(void* const* d_in, const int* in_sizes, int n_in,
                              void* d_out, int out_size, void* d_ws, size_t ws_size,
                              hipStream_t stream) {
    const float* features  = (const float*)d_in[0];
    const int*   edge_src  = (const int*)d_in[1];
    const int*   edge_dst  = (const int*)d_in[2];
    const int*   edge_type = (const int*)d_in[3];
    const float* e_emb     = (const float*)d_in[4];
    const float* W1e       = (const float*)d_in[5];
    const float* b1e       = (const float*)d_in[6];
    const float* W2e       = (const float*)d_in[7];
    const float* b2e       = (const float*)d_in[8];
    const float* W1s       = (const float*)d_in[9];
    const float* b1s       = (const float*)d_in[10];
    const float* W2s       = (const float*)d_in[11];
    const float* b2s       = (const float*)d_in[12];
    float* out = (float*)d_out;

    char* ws = (char*)d_ws;
    size_t off = 0;
    auto alloc = [&](size_t bytes) {
        char* p = ws + off;
        off += (bytes + 255) & ~(size_t)255;
        return p;
    };
    unsigned char*  G8       = (unsigned char*)alloc((size_t)NPADROW * 512);
    unsigned short* H        = (unsigned short*)alloc((size_t)NPADROW * 512 * 2);
    unsigned short* Fb       = (unsigned short*)alloc((size_t)N_TILES * 8192 * 2);
    unsigned short* Tb       = (unsigned short*)alloc(16 * 512 * 2);
    unsigned short* W1ebT    = (unsigned short*)alloc(512 * 128 * 2);
    unsigned short* W2eT     = (unsigned short*)alloc(128 * 512 * 2);
    unsigned short* W1sT     = (unsigned short*)alloc(256 * 128 * 2);
    unsigned short* W2sT     = (unsigned short*)alloc(128 * 256 * 2);
    int* counts      = (int*)alloc((size_t)N_PAD * 4);
    int* row_start   = (int*)alloc((size_t)N_PAD * 4);
    int* cursor      = (int*)alloc((size_t)N_PAD * 4);
    int* blocksum    = (int*)alloc(256 * 4);
    int* sorted_pack = (int*)alloc((size_t)N_EDGES * 4);

    k_prep_w<<<P_TOTAL / 256, 256, 0, stream>>>(e_emb, W1e, b1e, W2e, W1s, W2s, features,
                                                Tb, W1ebT, W2eT, W1sT, W2sT, Fb, counts);

    k_hist<<<(N_EDGES + 255) / 256, 256, 0, stream>>>(edge_dst, counts);
    k_scan1<<<NBLK, 256, 0, stream>>>(counts, blocksum);
    k_scan3<<<NBLK, 256, 0, stream>>>(counts, blocksum, row_start, cursor);
    k_scatter<<<(N_EDGES + 255) / 256, 256, 0, stream>>>(edge_src, edge_dst, edge_type,
                                                         cursor, sorted_pack);

    k_nodeGS<<<2 * GRID_HALF, 512, 0, stream>>>(Fb, W1ebT, G8, W1sT, b1s, W2sT, b2s, out);
    k_agg<<<AGG_BLOCKS, 256, 0, stream>>>(G8, Tb, row_start, sorted_pack, H);
    k_gemm_H<<<N_TILES, 512, 0, stream>>>(H, row_start, W2eT, b2e, out);
}